// Round 2
// baseline (427.731 us; speedup 1.0000x reference)
//
#include <hip/hip_runtime.h>
#include <cstddef>

#define T_TOT 8192
#define M_    512
#define HS_   512
#define D_    300
#define P_    8
#define TT    16

// ---------------- routing / compaction ----------------
__global__ __launch_bounds__(256) void route_kernel(
    const int* __restrict__ inp_word, const int* __restrict__ inp_pos,
    int* __restrict__ cnt, int* __restrict__ cnt_ns,
    int* __restrict__ perm, int* __restrict__ ns_list,
    float* __restrict__ out_word, float* __restrict__ out_maskm,
    float* __restrict__ out_maskn)
{
    int t = blockIdx.x * 256 + threadIdx.x;
    if (t >= T_TOT) return;
    int pp = inp_pos[t];
    out_maskm[t] = (pp < P_) ? 1.0f : 0.0f;
    out_maskn[t] = (pp < 2)  ? 1.0f : 0.0f;
    if (pp < P_) {
        int s = atomicAdd(&cnt[pp], 1);
        perm[pp * T_TOT + s] = t;
    } else {
        out_word[t] = (float)inp_word[t];
        int s = atomicAdd(cnt_ns, 1);
        ns_list[s] = t;
    }
}

// ---------------- base embedding gather for non-selected tokens ----------------
__global__ __launch_bounds__(128) void base_emb_kernel(
    const int* __restrict__ inp_word, const float* __restrict__ wemb,
    const int* __restrict__ cnt_ns, const int* __restrict__ ns_list,
    float* __restrict__ out_emb)
{
    int nns = *cnt_ns;
    for (int i = blockIdx.x; i < nns; i += gridDim.x) {
        int t = ns_list[i];
        int w = inp_word[t];
        if (threadIdx.x < 75) {  // 300 floats = 75 float4
            float4 v = *(const float4*)&wemb[(size_t)w * D_ + threadIdx.x * 4];
            *(float4*)&out_emb[(size_t)t * D_ + threadIdx.x * 4] = v;
        }
    }
}

// ---------------- per-expert heavy kernel ----------------
__global__ __launch_bounds__(256) void expert_kernel(
    const float* __restrict__ ctx,   const float* __restrict__ wemb,
    const float* __restrict__ dec_W, const float* __restrict__ dec_b,
    const int*   __restrict__ tgt,   const float* __restrict__ gumbel,
    const int*   __restrict__ cnt,   const int*   __restrict__ perm,
    float* __restrict__ out_word,    float* __restrict__ out_emb)
{
    int p = blockIdx.y;
    int count = cnt[p];
    int start = blockIdx.x * TT;
    if (start >= count) return;
    int n = min(TT, count - start);

    __shared__ float buf[TT][M_];     // 32 KB, reused: ctx tile -> logits -> sft
    __shared__ int   tok_ids[TT];
    __shared__ int   tw_s[M_];

    int tn = threadIdx.x;
    if (tn < TT) tok_ids[tn] = (tn < n) ? perm[p * T_TOT + start + tn] : -1;
    tw_s[tn]       = tgt[p * M_ + tn];
    tw_s[tn + 256] = tgt[p * M_ + tn + 256];
    __syncthreads();

    // stage ctx tile (16 tokens x 512) into LDS, float4 coalesced
    for (int i = tn; i < TT * (HS_ / 4); i += 256) {
        int tok = i >> 7;
        int pos = i & 127;
        int t = tok_ids[tok];
        float4 v = make_float4(0.f, 0.f, 0.f, 0.f);
        if (t >= 0) v = *(const float4*)&ctx[(size_t)t * HS_ + pos * 4];
        *(float4*)&buf[tok][pos * 4] = v;
    }
    __syncthreads();

    // ---- phase 1: logits[16][512] = ctx_tile @ dec_W[p]  (2 m-cols/thread) ----
    const float* Wp = dec_W + (size_t)p * HS_ * M_;
    int m0 = tn * 2;
    float accA[TT], accB[TT];
    #pragma unroll
    for (int k = 0; k < TT; ++k) { accA[k] = 0.f; accB[k] = 0.f; }

    for (int h4 = 0; h4 < HS_ / 4; ++h4) {
        float2 w0 = *(const float2*)&Wp[(size_t)(h4 * 4 + 0) * M_ + m0];
        float2 w1 = *(const float2*)&Wp[(size_t)(h4 * 4 + 1) * M_ + m0];
        float2 w2 = *(const float2*)&Wp[(size_t)(h4 * 4 + 2) * M_ + m0];
        float2 w3 = *(const float2*)&Wp[(size_t)(h4 * 4 + 3) * M_ + m0];
        #pragma unroll
        for (int k = 0; k < TT; ++k) {
            float4 c = *(const float4*)&buf[k][h4 * 4];   // LDS broadcast
            accA[k] = fmaf(c.x, w0.x, fmaf(c.y, w1.x, fmaf(c.z, w2.x, fmaf(c.w, w3.x, accA[k]))));
            accB[k] = fmaf(c.x, w0.y, fmaf(c.y, w1.y, fmaf(c.z, w2.y, fmaf(c.w, w3.y, accB[k]))));
        }
    }
    __syncthreads();   // done reading ctx from LDS

    float b0 = dec_b[p * M_ + m0];
    float b1 = dec_b[p * M_ + m0 + 1];
    #pragma unroll
    for (int k = 0; k < TT; ++k) {
        *(float2*)&buf[k][m0] = make_float2(accA[k] + b0, accB[k] + b1);
    }
    __syncthreads();

    // ---- phase 2: double softmax + gumbel argmax (one wave per 4 tokens) ----
    int wave = tn >> 6, lane = tn & 63;
    for (int tok = wave * 4; tok < wave * 4 + 4; ++tok) {
        if (tok >= n) continue;
        int t = tok_ids[tok];
        float l[8];
        #pragma unroll
        for (int j = 0; j < 8; ++j) l[j] = buf[tok][j * 64 + lane];
        float mx = l[0];
        #pragma unroll
        for (int j = 1; j < 8; ++j) mx = fmaxf(mx, l[j]);
        for (int off = 32; off; off >>= 1) mx = fmaxf(mx, __shfl_xor(mx, off, 64));

        float ex[8];
        float se = 0.f;
        #pragma unroll
        for (int j = 0; j < 8; ++j) { ex[j] = expf(l[j] - mx); se += ex[j]; }
        for (int off = 32; off; off >>= 1) se += __shfl_xor(se, off, 64);

        const float* gp = gumbel + ((size_t)p * T_TOT + t) * M_;
        float s[8];
        float bm = -3.0e38f;
        int   bi = 0x7fffffff;
        #pragma unroll
        for (int j = 0; j < 8; ++j) {
            float q  = ex[j] / se;
            float sv = logf(q + 1e-12f) + gp[j * 64 + lane];
            s[j] = sv;
            if (sv > bm) { bm = sv; bi = j * 64 + lane; }   // strict > keeps first index
        }
        for (int off = 32; off; off >>= 1) {
            float ov = __shfl_xor(bm, off, 64);
            int   oi = __shfl_xor(bi, off, 64);
            if (ov > bm || (ov == bm && oi < bi)) { bm = ov; bi = oi; }
        }

        float e2[8];
        float s2 = 0.f;
        #pragma unroll
        for (int j = 0; j < 8; ++j) { e2[j] = expf(s[j] - bm); s2 += e2[j]; }
        for (int off = 32; off; off >>= 1) s2 += __shfl_xor(s2, off, 64);

        #pragma unroll
        for (int j = 0; j < 8; ++j) buf[tok][j * 64 + lane] = e2[j] / s2;

        if (lane == 0) out_word[t] = (float)tw_s[bi];
    }
    __syncthreads();

    // ---- phase 3: emb[16][300] = sft @ gathered target embeddings ----
    if (tn < 150) {
        int d0 = tn * 2;
        float acA[TT], acB[TT];
        #pragma unroll
        for (int k = 0; k < TT; ++k) { acA[k] = 0.f; acB[k] = 0.f; }

        for (int m4 = 0; m4 < M_ / 4; ++m4) {
            int t0 = tw_s[m4 * 4 + 0];
            int t1 = tw_s[m4 * 4 + 1];
            int t2 = tw_s[m4 * 4 + 2];
            int t3 = tw_s[m4 * 4 + 3];
            float2 e0  = *(const float2*)&wemb[(size_t)t0 * D_ + d0];
            float2 e1  = *(const float2*)&wemb[(size_t)t1 * D_ + d0];
            float2 e2v = *(const float2*)&wemb[(size_t)t2 * D_ + d0];
            float2 e3  = *(const float2*)&wemb[(size_t)t3 * D_ + d0];
            #pragma unroll
            for (int k = 0; k < TT; ++k) {
                float4 sv = *(const float4*)&buf[k][m4 * 4];  // LDS broadcast
                acA[k] = fmaf(sv.x, e0.x, fmaf(sv.y, e1.x, fmaf(sv.z, e2v.x, fmaf(sv.w, e3.x, acA[k]))));
                acB[k] = fmaf(sv.x, e0.y, fmaf(sv.y, e1.y, fmaf(sv.z, e2v.y, fmaf(sv.w, e3.y, acB[k]))));
            }
        }
        #pragma unroll
        for (int k = 0; k < TT; ++k) {
            if (k < n) {
                int t = tok_ids[k];
                *(float2*)&out_emb[(size_t)t * D_ + d0] = make_float2(acA[k], acB[k]);
            }
        }
    }
}

// ---------------- launch ----------------
extern "C" void kernel_launch(void* const* d_in, const int* in_sizes, int n_in,
                              void* d_out, int out_size, void* d_ws, size_t ws_size,
                              hipStream_t stream)
{
    const int*   inp_word = (const int*)d_in[0];
    const int*   inp_pos  = (const int*)d_in[1];
    const float* ctx      = (const float*)d_in[2];
    const float* wemb     = (const float*)d_in[3];
    const float* dec_W    = (const float*)d_in[4];
    const float* dec_b    = (const float*)d_in[5];
    const int*   tgt      = (const int*)d_in[6];
    const float* gumbel   = (const float*)d_in[7];

    float* out       = (float*)d_out;
    float* out_word  = out;                          // [8192]
    float* out_emb   = out + T_TOT;                  // [8192][300]
    float* out_maskm = out + T_TOT + T_TOT * D_;     // [8192]
    float* out_maskn = out_maskm + T_TOT;            // [8192]

    int* cnt     = (int*)d_ws;        // [8]
    int* cnt_ns  = cnt + 8;           // [1]
    int* perm    = cnt + 16;          // [8][8192]
    int* ns_list = perm + P_ * T_TOT; // [8192]

    hipMemsetAsync(d_ws, 0, 64, stream);
    route_kernel<<<T_TOT / 256, 256, 0, stream>>>(
        inp_word, inp_pos, cnt, cnt_ns, perm, ns_list,
        out_word, out_maskm, out_maskn);
    base_emb_kernel<<<512, 128, 0, stream>>>(inp_word, wemb, cnt_ns, ns_list, out_emb);
    expert_kernel<<<dim3(512, P_), 256, 0, stream>>>(
        ctx, wemb, dec_W, dec_b, tgt, gumbel, cnt, perm, out_word, out_emb);
}

// Round 3
// 363.896 us; speedup vs baseline: 1.1754x; 1.1754x over previous
//
#include <hip/hip_runtime.h>
#include <cstddef>

#define T_TOT 8192
#define M_    512
#define HS_   512
#define D_    300
#define P_    8
#define TT    4
#define CNT_STRIDE 16   // pad global counters 64B apart (one L2 line each)

// ---------------- routing / compaction (hierarchical atomics) ----------------
__global__ __launch_bounds__(256) void route_kernel(
    const int* __restrict__ inp_word, const int* __restrict__ inp_pos,
    int* __restrict__ cnt, int* __restrict__ perm,
    float* __restrict__ out_word, float* __restrict__ out_maskm,
    float* __restrict__ out_maskn)
{
    __shared__ int lcnt[P_];
    __shared__ int lbase[P_];
    int tid = threadIdx.x;
    int t = blockIdx.x * 256 + tid;
    if (tid < P_) lcnt[tid] = 0;
    __syncthreads();

    int pp = inp_pos[t];
    out_maskm[t] = (pp < P_) ? 1.0f : 0.0f;
    out_maskn[t] = (pp < 2)  ? 1.0f : 0.0f;
    int loc = 0;
    if (pp < P_) {
        loc = atomicAdd(&lcnt[pp], 1);          // LDS atomic: cheap
    } else {
        out_word[t] = (float)inp_word[t];
    }
    __syncthreads();
    if (tid < P_) lbase[tid] = atomicAdd(&cnt[tid * CNT_STRIDE], lcnt[tid]);
    __syncthreads();
    if (pp < P_) perm[pp * T_TOT + lbase[pp] + loc] = t;
}

// ---------------- base embedding copy for non-selected tokens ----------------
__global__ __launch_bounds__(128) void base_emb_kernel(
    const int* __restrict__ inp_word, const int* __restrict__ inp_pos,
    const float* __restrict__ wemb, float* __restrict__ out_emb)
{
    int t = blockIdx.x;
    if (inp_pos[t] < P_) return;     // expert path owns this token
    int w = inp_word[t];
    if (threadIdx.x < 75) {          // 300 floats = 75 float4
        float4 v = *(const float4*)&wemb[(size_t)w * D_ + threadIdx.x * 4];
        *(float4*)&out_emb[(size_t)t * D_ + threadIdx.x * 4] = v;
    }
}

// ---------------- per-expert heavy kernel (TT=4 tokens/block) ----------------
__global__ __launch_bounds__(256, 4) void expert_kernel(
    const float* __restrict__ ctx,   const float* __restrict__ wemb,
    const float* __restrict__ dec_W, const float* __restrict__ dec_b,
    const int*   __restrict__ tgt,   const float* __restrict__ gumbel,
    const int*   __restrict__ cnt,   const int*   __restrict__ perm,
    float* __restrict__ out_word,    float* __restrict__ out_emb)
{
    int p = blockIdx.x;                   // expert == blockIdx.x -> flat%8 == p -> one expert per XCD
    int count = cnt[p * CNT_STRIDE];
    int start = blockIdx.y * TT;
    if (start >= count) return;
    int n = min(TT, count - start);

    __shared__ float buf[TT][M_];         // 8 KB, reused: ctx tile -> logits -> sft
    __shared__ int   tok_ids[TT];
    __shared__ int   tw_s[M_];

    int tn = threadIdx.x;
    if (tn < TT) tok_ids[tn] = (tn < n) ? perm[p * T_TOT + start + tn] : -1;
    tw_s[tn]       = tgt[p * M_ + tn];
    tw_s[tn + 256] = tgt[p * M_ + tn + 256];
    __syncthreads();

    // stage ctx tile (4 tokens x 512 floats = 512 float4s), 2 per thread
    #pragma unroll
    for (int it = 0; it < 2; ++it) {
        int idx  = tn + it * 256;
        int tok  = idx >> 7;
        int pos4 = idx & 127;
        int t = tok_ids[tok];
        float4 v = make_float4(0.f, 0.f, 0.f, 0.f);
        if (t >= 0) v = *(const float4*)&ctx[(size_t)t * HS_ + pos4 * 4];
        *(float4*)&buf[tok][pos4 * 4] = v;
    }
    __syncthreads();

    // ---- phase 1: logits[4][512] = ctx_tile @ dec_W[p]  (2 m-cols/thread) ----
    const float* Wp = dec_W + (size_t)p * HS_ * M_;
    int m0 = tn * 2;
    float accA[TT], accB[TT];
    #pragma unroll
    for (int k = 0; k < TT; ++k) { accA[k] = 0.f; accB[k] = 0.f; }

    for (int h4 = 0; h4 < HS_ / 4; ++h4) {
        float2 w0 = *(const float2*)&Wp[(size_t)(h4 * 4 + 0) * M_ + m0];
        float2 w1 = *(const float2*)&Wp[(size_t)(h4 * 4 + 1) * M_ + m0];
        float2 w2 = *(const float2*)&Wp[(size_t)(h4 * 4 + 2) * M_ + m0];
        float2 w3 = *(const float2*)&Wp[(size_t)(h4 * 4 + 3) * M_ + m0];
        #pragma unroll
        for (int k = 0; k < TT; ++k) {
            float4 c = *(const float4*)&buf[k][h4 * 4];   // LDS broadcast
            accA[k] = fmaf(c.x, w0.x, fmaf(c.y, w1.x, fmaf(c.z, w2.x, fmaf(c.w, w3.x, accA[k]))));
            accB[k] = fmaf(c.x, w0.y, fmaf(c.y, w1.y, fmaf(c.z, w2.y, fmaf(c.w, w3.y, accB[k]))));
        }
    }
    __syncthreads();   // all done reading ctx from LDS

    float b0 = dec_b[p * M_ + m0];
    float b1 = dec_b[p * M_ + m0 + 1];
    #pragma unroll
    for (int k = 0; k < TT; ++k) {
        *(float2*)&buf[k][m0] = make_float2(accA[k] + b0, accB[k] + b1);
    }
    __syncthreads();

    // ---- phase 2: double softmax + gumbel argmax (one wave per token) ----
    int wave = tn >> 6, lane = tn & 63;
    int tok = wave;
    if (tok < n) {
        int t = tok_ids[tok];
        float l[8];
        #pragma unroll
        for (int j = 0; j < 8; ++j) l[j] = buf[tok][j * 64 + lane];
        float mx = l[0];
        #pragma unroll
        for (int j = 1; j < 8; ++j) mx = fmaxf(mx, l[j]);
        for (int off = 32; off; off >>= 1) mx = fmaxf(mx, __shfl_xor(mx, off, 64));

        float ex[8];
        float se = 0.f;
        #pragma unroll
        for (int j = 0; j < 8; ++j) { ex[j] = expf(l[j] - mx); se += ex[j]; }
        for (int off = 32; off; off >>= 1) se += __shfl_xor(se, off, 64);

        const float* gp = gumbel + ((size_t)p * T_TOT + t) * M_;
        float s[8];
        float bm = -3.0e38f;
        int   bi = 0x7fffffff;
        #pragma unroll
        for (int j = 0; j < 8; ++j) {
            float q  = ex[j] / se;
            float sv = logf(q + 1e-12f) + gp[j * 64 + lane];
            s[j] = sv;
            if (sv > bm) { bm = sv; bi = j * 64 + lane; }   // strict > keeps first index
        }
        for (int off = 32; off; off >>= 1) {
            float ov = __shfl_xor(bm, off, 64);
            int   oi = __shfl_xor(bi, off, 64);
            if (ov > bm || (ov == bm && oi < bi)) { bm = ov; bi = oi; }
        }

        float e2[8];
        float s2 = 0.f;
        #pragma unroll
        for (int j = 0; j < 8; ++j) { e2[j] = expf(s[j] - bm); s2 += e2[j]; }
        for (int off = 32; off; off >>= 1) s2 += __shfl_xor(s2, off, 64);

        #pragma unroll
        for (int j = 0; j < 8; ++j) buf[tok][j * 64 + lane] = e2[j] / s2;

        if (lane == 0) out_word[t] = (float)tw_s[bi];
    }
    __syncthreads();

    // ---- phase 3: emb[4][300] = sft @ gathered target embeddings ----
    if (tn < 150) {
        int d0 = tn * 2;
        float acA[TT], acB[TT];
        #pragma unroll
        for (int k = 0; k < TT; ++k) { acA[k] = 0.f; acB[k] = 0.f; }

        #pragma unroll 2
        for (int m4 = 0; m4 < M_ / 4; ++m4) {
            int t0 = tw_s[m4 * 4 + 0];
            int t1 = tw_s[m4 * 4 + 1];
            int t2 = tw_s[m4 * 4 + 2];
            int t3 = tw_s[m4 * 4 + 3];
            float2 e0  = *(const float2*)&wemb[(size_t)t0 * D_ + d0];
            float2 e1  = *(const float2*)&wemb[(size_t)t1 * D_ + d0];
            float2 e2v = *(const float2*)&wemb[(size_t)t2 * D_ + d0];
            float2 e3  = *(const float2*)&wemb[(size_t)t3 * D_ + d0];
            #pragma unroll
            for (int k = 0; k < TT; ++k) {
                float4 sv = *(const float4*)&buf[k][m4 * 4];  // LDS broadcast
                acA[k] = fmaf(sv.x, e0.x, fmaf(sv.y, e1.x, fmaf(sv.z, e2v.x, fmaf(sv.w, e3.x, acA[k]))));
                acB[k] = fmaf(sv.x, e0.y, fmaf(sv.y, e1.y, fmaf(sv.z, e2v.y, fmaf(sv.w, e3.y, acB[k]))));
            }
        }
        #pragma unroll
        for (int k = 0; k < TT; ++k) {
            if (k < n) {
                int t = tok_ids[k];
                *(float2*)&out_emb[(size_t)t * D_ + d0] = make_float2(acA[k], acB[k]);
            }
        }
    }
}

// ---------------- launch ----------------
extern "C" void kernel_launch(void* const* d_in, const int* in_sizes, int n_in,
                              void* d_out, int out_size, void* d_ws, size_t ws_size,
                              hipStream_t stream)
{
    const int*   inp_word = (const int*)d_in[0];
    const int*   inp_pos  = (const int*)d_in[1];
    const float* ctx      = (const float*)d_in[2];
    const float* wemb     = (const float*)d_in[3];
    const float* dec_W    = (const float*)d_in[4];
    const float* dec_b    = (const float*)d_in[5];
    const int*   tgt      = (const int*)d_in[6];
    const float* gumbel   = (const float*)d_in[7];

    float* out       = (float*)d_out;
    float* out_word  = out;                          // [8192]
    float* out_emb   = out + T_TOT;                  // [8192][300]
    float* out_maskm = out + T_TOT + T_TOT * D_;     // [8192]
    float* out_maskn = out_maskm + T_TOT;            // [8192]

    int* cnt  = (int*)d_ws;                          // [8 * CNT_STRIDE]
    int* perm = cnt + P_ * CNT_STRIDE;               // [8][8192]

    hipMemsetAsync(d_ws, 0, P_ * CNT_STRIDE * sizeof(int), stream);
    route_kernel<<<T_TOT / 256, 256, 0, stream>>>(
        inp_word, inp_pos, cnt, perm, out_word, out_maskm, out_maskn);
    base_emb_kernel<<<T_TOT, 128, 0, stream>>>(inp_word, inp_pos, wemb, out_emb);
    // grid (8, 2048): blockIdx.x == expert == flattened_id % 8 == XCD  -> each
    // XCD's L2 caches exactly one expert's 1 MB dec_W panel.
    expert_kernel<<<dim3(P_, T_TOT / TT), 256, 0, stream>>>(
        ctx, wemb, dec_W, dec_b, tgt, gumbel, cnt, perm, out_word, out_emb);
}

// Round 4
// 340.267 us; speedup vs baseline: 1.2570x; 1.0694x over previous
//
#include <hip/hip_runtime.h>
#include <cstddef>

#define T_TOT 8192
#define M_    512
#define HS_   512
#define D_    300
#define P_    8
#define TT    8
#define KSTEP 8                 // h rows per staged W tile
#define NSTEP (HS_ / KSTEP)     // 64
#define CNT_STRIDE 16           // pad global counters 64B apart

__device__ __forceinline__ void gload_lds16(const float* g, float* l) {
    __builtin_amdgcn_global_load_lds(
        (const __attribute__((address_space(1))) unsigned int*)g,
        (__attribute__((address_space(3))) unsigned int*)l, 16, 0, 0);
}

// ---------------- routing / compaction (hierarchical atomics) ----------------
__global__ __launch_bounds__(256) void route_kernel(
    const int* __restrict__ inp_word, const int* __restrict__ inp_pos,
    int* __restrict__ cnt, int* __restrict__ perm,
    float* __restrict__ out_word, float* __restrict__ out_maskm,
    float* __restrict__ out_maskn)
{
    __shared__ int lcnt[P_];
    __shared__ int lbase[P_];
    int tid = threadIdx.x;
    int t = blockIdx.x * 256 + tid;
    if (tid < P_) lcnt[tid] = 0;
    __syncthreads();

    int pp = inp_pos[t];
    out_maskm[t] = (pp < P_) ? 1.0f : 0.0f;
    out_maskn[t] = (pp < 2)  ? 1.0f : 0.0f;
    int loc = 0;
    if (pp < P_) {
        loc = atomicAdd(&lcnt[pp], 1);
    } else {
        out_word[t] = (float)inp_word[t];
    }
    __syncthreads();
    if (tid < P_) lbase[tid] = atomicAdd(&cnt[tid * CNT_STRIDE], lcnt[tid]);
    __syncthreads();
    if (pp < P_) perm[pp * T_TOT + lbase[pp] + loc] = t;
}

// ---------------- base embedding copy for non-selected tokens ----------------
__global__ __launch_bounds__(128) void base_emb_kernel(
    const int* __restrict__ inp_word, const int* __restrict__ inp_pos,
    const float* __restrict__ wemb, float* __restrict__ out_emb)
{
    int t = blockIdx.x;
    if (inp_pos[t] < P_) return;
    int w = inp_word[t];
    if (threadIdx.x < 75) {          // 300 floats = 75 float4
        float4 v = *(const float4*)&wemb[(size_t)w * D_ + threadIdx.x * 4];
        *(float4*)&out_emb[(size_t)t * D_ + threadIdx.x * 4] = v;
    }
}

// ---------------- per-expert heavy kernel (TT=8, W via global_load_lds) -----
__global__ __launch_bounds__(256, 3) void expert_kernel(
    const float* __restrict__ ctx,   const float* __restrict__ wemb,
    const float* __restrict__ dec_W, const float* __restrict__ dec_b,
    const int*   __restrict__ tgt,   const float* __restrict__ gumbel,
    const int*   __restrict__ cnt,   const int*   __restrict__ perm,
    float* __restrict__ out_word,    float* __restrict__ out_emb)
{
    int p = blockIdx.x;                   // expert == flat%8 == XCD (L2 pin)
    int count = cnt[p * CNT_STRIDE];
    int start = blockIdx.y * TT;
    if (start >= count) return;
    int n = min(TT, count - start);

    __shared__ float ctxb[TT][HS_];            // 16 KB: ctx tile -> logits -> sft
    __shared__ float wbuf[2][KSTEP][M_];       // 32 KB: double-buffered W tiles
    __shared__ int   tok_ids[TT];
    __shared__ int   tw_s[M_];

    int tn = threadIdx.x;
    if (tn < TT) tok_ids[tn] = (tn < n) ? perm[p * T_TOT + start + tn] : -1;
    tw_s[tn]       = tgt[p * M_ + tn];
    tw_s[tn + 256] = tgt[p * M_ + tn + 256];
    __syncthreads();

    const float* Wp = dec_W + (size_t)p * HS_ * M_;

    // prologue: stage W tile 0 (16 KB, DMA) ...
    #pragma unroll
    for (int r = 0; r < 4; ++r)
        gload_lds16(Wp + r * 1024 + tn * 4, &wbuf[0][0][0] + r * 1024 + tn * 4);

    // ... while also staging the ctx tile (8 tokens x 512 = 1024 float4s)
    #pragma unroll
    for (int it = 0; it < 4; ++it) {
        int idx  = tn + it * 256;
        int tok  = idx >> 7;
        int pos4 = idx & 127;
        int t = tok_ids[tok];
        float4 v = make_float4(0.f, 0.f, 0.f, 0.f);
        if (t >= 0) v = *(const float4*)&ctx[(size_t)t * HS_ + pos4 * 4];
        *(float4*)&ctxb[tok][pos4 * 4] = v;
    }
    __syncthreads();   // drains vmcnt (W tile 0 landed) + ctx stores

    // ---- phase 1: logits[8][512] = ctx_tile @ dec_W[p]  (2 m-cols/thread) ---
    int m0 = tn * 2;
    float accA[TT], accB[TT];
    #pragma unroll
    for (int k = 0; k < TT; ++k) { accA[k] = 0.f; accB[k] = 0.f; }

    int cur = 0;
    for (int step = 0; step < NSTEP; ++step) {
        // issue next W tile's DMA first (hides under this step's FMAs)
        if (step + 1 < NSTEP) {
            const float* src = Wp + (size_t)(step + 1) * KSTEP * M_;
            float* dst = &wbuf[cur ^ 1][0][0];
            #pragma unroll
            for (int r = 0; r < 4; ++r)
                gload_lds16(src + r * 1024 + tn * 4, dst + r * 1024 + tn * 4);
        }
        #pragma unroll
        for (int h4 = 0; h4 < KSTEP / 4; ++h4) {
            float2 w0 = *(const float2*)&wbuf[cur][h4 * 4 + 0][m0];
            float2 w1 = *(const float2*)&wbuf[cur][h4 * 4 + 1][m0];
            float2 w2 = *(const float2*)&wbuf[cur][h4 * 4 + 2][m0];
            float2 w3 = *(const float2*)&wbuf[cur][h4 * 4 + 3][m0];
            #pragma unroll
            for (int k = 0; k < TT; ++k) {
                float4 c = *(const float4*)&ctxb[k][step * KSTEP + h4 * 4]; // broadcast
                accA[k] = fmaf(c.x, w0.x, fmaf(c.y, w1.x, fmaf(c.z, w2.x, fmaf(c.w, w3.x, accA[k]))));
                accB[k] = fmaf(c.x, w0.y, fmaf(c.y, w1.y, fmaf(c.z, w2.y, fmaf(c.w, w3.y, accB[k]))));
            }
        }
        __syncthreads();   // next tile landed; everyone done with wbuf[cur]
        cur ^= 1;
    }

    // logits + bias -> reuse ctxb as the logits/sft buffer
    float b0 = dec_b[p * M_ + m0];
    float b1 = dec_b[p * M_ + m0 + 1];
    #pragma unroll
    for (int k = 0; k < TT; ++k) {
        *(float2*)&ctxb[k][m0] = make_float2(accA[k] + b0, accB[k] + b1);
    }
    __syncthreads();

    // ---- phase 2: double softmax + gumbel argmax (one wave per 2 tokens) ----
    int wave = tn >> 6, lane = tn & 63;
    for (int tok = wave * 2; tok < wave * 2 + 2; ++tok) {
        if (tok >= n) continue;
        int t = tok_ids[tok];
        float l[8];
        #pragma unroll
        for (int j = 0; j < 8; ++j) l[j] = ctxb[tok][j * 64 + lane];
        float mx = l[0];
        #pragma unroll
        for (int j = 1; j < 8; ++j) mx = fmaxf(mx, l[j]);
        for (int off = 32; off; off >>= 1) mx = fmaxf(mx, __shfl_xor(mx, off, 64));

        float ex[8];
        float se = 0.f;
        #pragma unroll
        for (int j = 0; j < 8; ++j) { ex[j] = expf(l[j] - mx); se += ex[j]; }
        for (int off = 32; off; off >>= 1) se += __shfl_xor(se, off, 64);

        const float* gp = gumbel + ((size_t)p * T_TOT + t) * M_;
        float s[8];
        float bm = -3.0e38f;
        int   bi = 0x7fffffff;
        #pragma unroll
        for (int j = 0; j < 8; ++j) {
            float q  = ex[j] / se;
            float sv = logf(q + 1e-12f) + gp[j * 64 + lane];
            s[j] = sv;
            if (sv > bm) { bm = sv; bi = j * 64 + lane; }   // strict > = first index
        }
        for (int off = 32; off; off >>= 1) {
            float ov = __shfl_xor(bm, off, 64);
            int   oi = __shfl_xor(bi, off, 64);
            if (ov > bm || (ov == bm && oi < bi)) { bm = ov; bi = oi; }
        }

        float e2[8];
        float s2 = 0.f;
        #pragma unroll
        for (int j = 0; j < 8; ++j) { e2[j] = expf(s[j] - bm); s2 += e2[j]; }
        for (int off = 32; off; off >>= 1) s2 += __shfl_xor(s2, off, 64);

        #pragma unroll
        for (int j = 0; j < 8; ++j) ctxb[tok][j * 64 + lane] = e2[j] / s2;

        if (lane == 0) out_word[t] = (float)tw_s[bi];
    }
    __syncthreads();

    // ---- phase 3: emb[8][300] = sft @ gathered target embeddings ----
    if (tn < 150) {
        int d0 = tn * 2;
        float acA[TT], acB[TT];
        #pragma unroll
        for (int k = 0; k < TT; ++k) { acA[k] = 0.f; acB[k] = 0.f; }

        #pragma unroll 2
        for (int m4 = 0; m4 < M_ / 4; ++m4) {
            int t0 = tw_s[m4 * 4 + 0];
            int t1 = tw_s[m4 * 4 + 1];
            int t2 = tw_s[m4 * 4 + 2];
            int t3 = tw_s[m4 * 4 + 3];
            float2 e0  = *(const float2*)&wemb[(size_t)t0 * D_ + d0];
            float2 e1  = *(const float2*)&wemb[(size_t)t1 * D_ + d0];
            float2 e2v = *(const float2*)&wemb[(size_t)t2 * D_ + d0];
            float2 e3  = *(const float2*)&wemb[(size_t)t3 * D_ + d0];
            #pragma unroll
            for (int k = 0; k < TT; ++k) {
                float4 sv = *(const float4*)&ctxb[k][m4 * 4];  // LDS broadcast
                acA[k] = fmaf(sv.x, e0.x, fmaf(sv.y, e1.x, fmaf(sv.z, e2v.x, fmaf(sv.w, e3.x, acA[k]))));
                acB[k] = fmaf(sv.x, e0.y, fmaf(sv.y, e1.y, fmaf(sv.z, e2v.y, fmaf(sv.w, e3.y, acB[k]))));
            }
        }
        #pragma unroll
        for (int k = 0; k < TT; ++k) {
            if (k < n) {
                int t = tok_ids[k];
                *(float2*)&out_emb[(size_t)t * D_ + d0] = make_float2(acA[k], acB[k]);
            }
        }
    }
}

// ---------------- launch ----------------
extern "C" void kernel_launch(void* const* d_in, const int* in_sizes, int n_in,
                              void* d_out, int out_size, void* d_ws, size_t ws_size,
                              hipStream_t stream)
{
    const int*   inp_word = (const int*)d_in[0];
    const int*   inp_pos  = (const int*)d_in[1];
    const float* ctx      = (const float*)d_in[2];
    const float* wemb     = (const float*)d_in[3];
    const float* dec_W    = (const float*)d_in[4];
    const float* dec_b    = (const float*)d_in[5];
    const int*   tgt      = (const int*)d_in[6];
    const float* gumbel   = (const float*)d_in[7];

    float* out       = (float*)d_out;
    float* out_word  = out;                          // [8192]
    float* out_emb   = out + T_TOT;                  // [8192][300]
    float* out_maskm = out + T_TOT + T_TOT * D_;     // [8192]
    float* out_maskn = out_maskm + T_TOT;            // [8192]

    int* cnt  = (int*)d_ws;                          // [8 * CNT_STRIDE]
    int* perm = cnt + P_ * CNT_STRIDE;               // [8][8192]

    hipMemsetAsync(d_ws, 0, P_ * CNT_STRIDE * sizeof(int), stream);
    route_kernel<<<T_TOT / 256, 256, 0, stream>>>(
        inp_word, inp_pos, cnt, perm, out_word, out_maskm, out_maskn);
    base_emb_kernel<<<T_TOT, 128, 0, stream>>>(inp_word, inp_pos, wemb, out_emb);
    // grid (8, 1024): blockIdx.x == expert == flattened_id % 8 == XCD -> each
    // XCD's L2 caches exactly one expert's 1 MB dec_W panel.
    expert_kernel<<<dim3(P_, T_TOT / TT), 256, 0, stream>>>(
        ctx, wemb, dec_W, dec_b, tgt, gumbel, cnt, perm, out_word, out_emb);
}